// Round 2
// baseline (278.872 us; speedup 1.0000x reference)
//
#include <hip/hip_runtime.h>

typedef unsigned short u16;
typedef __attribute__((ext_vector_type(8))) __bf16 bf16x8;
typedef __attribute__((ext_vector_type(4))) _Float16 f16x4;
typedef __attribute__((ext_vector_type(8))) _Float16 f16x8;
typedef __attribute__((ext_vector_type(4))) float f32x4;

#define BB 4
#define SS 1024
#define DD 2048
#define HH 32
#define KVHN 8
#define HDIM 64

__device__ __forceinline__ u16 f2b(float f) {
    union { float f; unsigned u; } v; v.f = f;
    unsigned r = v.u + 0x7FFFu + ((v.u >> 16) & 1u);
    return (u16)(r >> 16);
}
__device__ __forceinline__ float b2f(u16 h) {
    union { unsigned u; float f; } v; v.u = ((unsigned)h) << 16; return v.f;
}

__device__ __forceinline__ f32x4 mfma16(bf16x8 a, bf16x8 b, f32x4 c) {
    return __builtin_amdgcn_mfma_f32_16x16x32_bf16(a, b, c, 0, 0, 0);
}
__device__ __forceinline__ f32x4 mfma16h(f16x8 a, f16x8 b, f32x4 c) {
    return __builtin_amdgcn_mfma_f32_16x16x32_f16(a, b, c, 0, 0, 0);
}

__device__ __forceinline__ void async_cp16(const void* g, void* l) {
    __builtin_amdgcn_global_load_lds((__attribute__((address_space(1))) void*)g,
                                     (__attribute__((address_space(3))) void*)l,
                                     16, 0, 0);
}

// raw barrier WITHOUT the compiler's vmcnt(0) drain
__device__ __forceinline__ void block_sync() {
    asm volatile("" ::: "memory");
    __builtin_amdgcn_s_barrier();
    asm volatile("" ::: "memory");
}

// pack 8 floats -> f16x8 via v_cvt_pkrtz
__device__ __forceinline__ f16x8 pack8_f16(const float* p) {
    union { unsigned u[4]; f16x8 v; } pu;
    pu.u[0] = __builtin_bit_cast(unsigned, __builtin_amdgcn_cvt_pkrtz(p[0], p[1]));
    pu.u[1] = __builtin_bit_cast(unsigned, __builtin_amdgcn_cvt_pkrtz(p[2], p[3]));
    pu.u[2] = __builtin_bit_cast(unsigned, __builtin_amdgcn_cvt_pkrtz(p[4], p[5]));
    pu.u[3] = __builtin_bit_cast(unsigned, __builtin_amdgcn_cvt_pkrtz(p[6], p[7]));
    return pu.v;
}

// ---------------- cast x (fp32 -> bf16) ----------------
__global__ __launch_bounds__(256) void cast_x_kernel(const float* __restrict__ x,
                                                     u16* __restrict__ xb) {
    int i = (blockIdx.x * 256 + threadIdx.x) * 4;
    float4 v = *(const float4*)(x + i);
    unsigned r0 = (unsigned)f2b(v.x) | ((unsigned)f2b(v.y) << 16);
    unsigned r1 = (unsigned)f2b(v.z) | ((unsigned)f2b(v.w) << 16);
    *(uint2*)(xb + i) = make_uint2(r0, r1);
}

// ---------------- all weight transposes in one launch ----------------
__global__ __launch_bounds__(256) void wtrans_all_kernel(const float* __restrict__ Wq,
                                                         const float* __restrict__ Wk,
                                                         const float* __restrict__ Wv,
                                                         const float* __restrict__ Wo,
                                                         u16* __restrict__ Wqkvt,
                                                         u16* __restrict__ Wot) {
    __shared__ float tile[32][33];
    int z = blockIdx.z;
    const float* W = (z == 0) ? Wq : (z == 1) ? Wk : (z == 2) ? Wv : Wo;
    int N = (z == 1 || z == 2) ? 512 : 2048;
    int n_off = (z == 1) ? 2048 : (z == 2) ? 2560 : 0;
    u16* Wt = (z == 3) ? Wot : Wqkvt;
    int n0 = blockIdx.x * 32;
    if (n0 >= N) return;
    int k0 = blockIdx.y * 32;
    int tid = threadIdx.x;
    int nj = tid & 31;
    int ki = tid >> 5;
#pragma unroll
    for (int it = 0; it < 4; it++) {
        int kk = it * 8 + ki;
        tile[kk][nj] = W[(size_t)(k0 + kk) * N + n0 + nj];
    }
    __syncthreads();
#pragma unroll
    for (int it = 0; it < 4; it++) {
        int nn = it * 8 + ki;
        Wt[(size_t)(n0 + nn + n_off) * 2048 + k0 + nj] = f2b(tile[nj][nn]);
    }
}

// ============================================================================
// GEMM (qkv): C[4096][3072](bf16) = A[4096][2048] * Bt[3072][2048]^T
// 128x192 tile, BK=32, 4 waves (2Mx2N, wave-tile 64x96), ring-4 LDS (80 KiB),
// 512 blocks = 2 blocks/CU, XCD super-tiling (8m x 8n per XCD), vmcnt(10).
// ============================================================================
__global__ __launch_bounds__(256, 2) void gemm_qkv(const u16* __restrict__ A,
                                                   const u16* __restrict__ Bt,
                                                   u16* __restrict__ C) {
    __shared__ __align__(16) u16 Ls[4][10240];  // per buf: A 128x32 @0, B 192x32 @4096
    const int tid = threadIdx.x;
    const int lane = tid & 63;
    const int w = tid >> 6;

    // XCD-aware mapping: 512 blocks, bid&7 = XCD; each XCD owns an 8x8 tile super-tile
    const int bid = blockIdx.x;
    const int xcd = bid & 7;
    const int loc = bid >> 3;
    const int mt = (xcd & 3) * 8 + (loc & 7);   // 0..31
    const int nt = (xcd >> 2) * 8 + (loc >> 3); // 0..15
    const int m0 = mt * 128;
    const int n0 = nt * 192;

    const int wm = (w >> 1) * 64;
    const int wn = (w & 1) * 96;
    const int lr = lane & 15;
    const int lg = lane >> 4;

    // staging: per wave A rows [w*32, w*32+32), B rows [w*48, w*48+48); 5 loads/wave/tile
    const int srow = lane >> 2;
    const int ar = w * 32 + srow;
    const int ag = (lane & 3) ^ ((ar >> 1) & 3);
    const u16* apA = A + (size_t)(m0 + ar) * 2048 + ag * 8;
    const int br = w * 48 + srow;
    const int bg = (lane & 3) ^ ((br >> 1) & 3);
    const u16* apB = Bt + (size_t)(n0 + br) * 2048 + bg * 8;

#define QSTAGE(pb_, kt_)                                                             \
    {                                                                                \
        async_cp16(apA + (kt_) * 32,             &Ls[pb_][w * 1024]);                \
        async_cp16(apA + (kt_) * 32 + 16 * 2048, &Ls[pb_][w * 1024 + 512]);          \
        async_cp16(apB + (kt_) * 32,             &Ls[pb_][4096 + w * 1536]);         \
        async_cp16(apB + (kt_) * 32 + 16 * 2048, &Ls[pb_][4096 + w * 1536 + 512]);   \
        async_cp16(apB + (kt_) * 32 + 32 * 2048, &Ls[pb_][4096 + w * 1536 + 1024]);  \
    }

    f32x4 acc[4][6];
    const f32x4 zero4 = {0.f, 0.f, 0.f, 0.f};
#pragma unroll
    for (int i = 0; i < 4; i++)
#pragma unroll
        for (int j = 0; j < 6; j++) acc[i][j] = zero4;

    // prologue: tiles 0,1,2 in flight (15 loads/wave); certify tile 0
    QSTAGE(0, 0);
    QSTAGE(1, 1);
    QSTAGE(2, 2);
    asm volatile("s_waitcnt vmcnt(10)" ::: "memory");
    block_sync();

#pragma unroll 4
    for (int t = 0; t < 64; ++t) {
        const int bufi = t & 3;
        const int pb = (t + 3) & 3;
        const int pt = (t + 3) & 63;  // tail wrap: redundant re-stage keeps vmcnt uniform
        const u16* Ab = &Ls[bufi][0];
        const u16* Bb = &Ls[bufi][4096];

        bf16x8 bfr[6], af[4];
#pragma unroll
        for (int ni = 0; ni < 6; ni++) {
            int r = wn + ni * 16 + lr;
            bfr[ni] = *(const bf16x8*)(Bb + r * 32 + ((lg ^ ((r >> 1) & 3)) * 8));
        }
#pragma unroll
        for (int mi = 0; mi < 4; mi++) {
            int r = wm + mi * 16 + lr;
            af[mi] = *(const bf16x8*)(Ab + r * 32 + ((lg ^ ((r >> 1) & 3)) * 8));
        }
        QSTAGE(pb, pt);
        __builtin_amdgcn_s_setprio(1);
#pragma unroll
        for (int mi = 0; mi < 4; mi++)
#pragma unroll
            for (int ni = 0; ni < 6; ni++)
                acc[mi][ni] = mfma16(af[mi], bfr[ni], acc[mi][ni]);
        __builtin_amdgcn_s_setprio(0);

        // certify tile t+1 (tiles t+2,t+3 = 10 newest stay in flight)
        asm volatile("s_waitcnt vmcnt(10)" ::: "memory");
        block_sync();
    }
    asm volatile("s_waitcnt vmcnt(0)" ::: "memory");

    const int lq = lg * 4;
#pragma unroll
    for (int mi = 0; mi < 4; mi++)
#pragma unroll
        for (int ni = 0; ni < 6; ni++)
#pragma unroll
            for (int i = 0; i < 4; i++) {
                int r = m0 + wm + mi * 16 + lq + i;
                int c = n0 + wn + ni * 16 + lr;
                C[(size_t)r * 3072 + c] = f2b(acc[mi][ni][i]);
            }
#undef QSTAGE
}

// ============================================================================
// GEMM (out): C[4096][2048](f32) = A[4096][2048](bf16) * Bt[2048][2048]^T
// 128x128 tile, BK=32, 4 waves (2Mx2N, wave-tile 64x64), ring-4 LDS (64 KiB),
// 512 blocks = 2 blocks/CU, XCD super-tiling, vmcnt(8).
// ============================================================================
__global__ __launch_bounds__(256, 2) void gemm_out(const u16* __restrict__ A,
                                                   const u16* __restrict__ Bt,
                                                   float* __restrict__ C) {
    __shared__ __align__(16) u16 Ls[4][8192];  // per buf: A 128x32 @0, B 128x32 @4096
    const int tid = threadIdx.x;
    const int lane = tid & 63;
    const int w = tid >> 6;

    const int bid = blockIdx.x;
    const int xcd = bid & 7;
    const int loc = bid >> 3;
    const int mt = (xcd & 3) * 8 + (loc & 7);   // 0..31
    const int nt = (xcd >> 2) * 8 + (loc >> 3); // 0..15
    const int m0 = mt * 128;
    const int n0 = nt * 128;

    const int wm = (w >> 1) * 64;
    const int wn = (w & 1) * 64;
    const int lr = lane & 15;
    const int lg = lane >> 4;

    const int srow = lane >> 2;
    const int ar = w * 32 + srow;
    const int ag = (lane & 3) ^ ((ar >> 1) & 3);
    const u16* apA = A + (size_t)(m0 + ar) * 2048 + ag * 8;
    const u16* apB = Bt + (size_t)(n0 + ar) * 2048 + ag * 8;

#define OSTAGE(pb_, kt_)                                                             \
    {                                                                                \
        async_cp16(apA + (kt_) * 32,             &Ls[pb_][w * 1024]);                \
        async_cp16(apA + (kt_) * 32 + 16 * 2048, &Ls[pb_][w * 1024 + 512]);          \
        async_cp16(apB + (kt_) * 32,             &Ls[pb_][4096 + w * 1024]);         \
        async_cp16(apB + (kt_) * 32 + 16 * 2048, &Ls[pb_][4096 + w * 1024 + 512]);   \
    }

    f32x4 acc[4][4];
    const f32x4 zero4 = {0.f, 0.f, 0.f, 0.f};
#pragma unroll
    for (int i = 0; i < 4; i++)
#pragma unroll
        for (int j = 0; j < 4; j++) acc[i][j] = zero4;

    OSTAGE(0, 0);
    OSTAGE(1, 1);
    OSTAGE(2, 2);
    asm volatile("s_waitcnt vmcnt(8)" ::: "memory");
    block_sync();

#pragma unroll 4
    for (int t = 0; t < 64; ++t) {
        const int bufi = t & 3;
        const int pb = (t + 3) & 3;
        const int pt = (t + 3) & 63;
        const u16* Ab = &Ls[bufi][0];
        const u16* Bb = &Ls[bufi][4096];

        bf16x8 bfr[4], af[4];
#pragma unroll
        for (int ni = 0; ni < 4; ni++) {
            int r = wn + ni * 16 + lr;
            bfr[ni] = *(const bf16x8*)(Bb + r * 32 + ((lg ^ ((r >> 1) & 3)) * 8));
        }
#pragma unroll
        for (int mi = 0; mi < 4; mi++) {
            int r = wm + mi * 16 + lr;
            af[mi] = *(const bf16x8*)(Ab + r * 32 + ((lg ^ ((r >> 1) & 3)) * 8));
        }
        OSTAGE(pb, pt);
        __builtin_amdgcn_s_setprio(1);
#pragma unroll
        for (int mi = 0; mi < 4; mi++)
#pragma unroll
            for (int ni = 0; ni < 4; ni++)
                acc[mi][ni] = mfma16(af[mi], bfr[ni], acc[mi][ni]);
        __builtin_amdgcn_s_setprio(0);

        asm volatile("s_waitcnt vmcnt(8)" ::: "memory");
        block_sync();
    }
    asm volatile("s_waitcnt vmcnt(0)" ::: "memory");

    const int lq = lg * 4;
#pragma unroll
    for (int mi = 0; mi < 4; mi++)
#pragma unroll
        for (int ni = 0; ni < 4; ni++)
#pragma unroll
            for (int i = 0; i < 4; i++) {
                int r = m0 + wm + mi * 16 + lq + i;
                int c = n0 + wn + ni * 16 + lr;
                C[(size_t)r * 2048 + c] = acc[mi][ni][i];
            }
#undef OSTAGE
}

// ---------------- RoPE + reshape.  Q pre-scaled by 0.125*log2(e).
// K rows permuted within each 32-seq block so QK S-tiles emit the K=32 PV B-layout:
// row = (s&~31) + (rr>=4)*16 + ((s>>3)&3)*4 + (rr&3), rr = s&7.
__global__ __launch_bounds__(256) void rope_kernel(const u16* __restrict__ QKV,
                                                   const float* __restrict__ cosT,
                                                   const float* __restrict__ sinT,
                                                   u16* __restrict__ Qh,
                                                   u16* __restrict__ Kh) {
    const float QSC = 0.125f * 1.44269504088896f;
    int idx = blockIdx.x * 256 + threadIdx.x;
    int d = idx & 31;
    int t = idx >> 5;
    int hh = t % 40;
    int row = t / 40;
    int s = row & (SS - 1);
    int b = row >> 10;
    float c = cosT[s * HDIM + d];
    float sn = sinT[s * HDIM + d];
    if (hh < 32) {
        const u16* src = QKV + (size_t)row * 3072 + hh * 64 + d;
        float x1 = b2f(src[0]), x2 = b2f(src[32]);
        u16* dst = Qh + ((size_t)(b * HH + hh) * SS + s) * 64 + d;
        dst[0] = f2b((x1 * c - x2 * sn) * QSC);
        dst[32] = f2b((x2 * c + x1 * sn) * QSC);
    } else {
        int g = hh - 32;
        const u16* src = QKV + (size_t)row * 3072 + 2048 + g * 64 + d;
        float x1 = b2f(src[0]), x2 = b2f(src[32]);
        int rr = s & 7;
        int kpos = (s & ~31) + ((rr >= 4) ? 16 : 0) + ((s >> 3) & 3) * 4 + (rr & 3);
        u16* dst = Kh + ((size_t)(b * KVHN + g) * SS + kpos) * 64 + d;
        dst[0] = f2b(x1 * c - x2 * sn);
        dst[32] = f2b(x2 * c + x1 * sn);
    }
}

// ---------------- V transpose: QKV bf16 -> Vt[B][KVH][64][S] f16 (identity kv order) ----------------
__global__ __launch_bounds__(256) void vtrans_kernel(const u16* __restrict__ QKV,
                                                     u16* __restrict__ Vt) {
    __shared__ u16 tile[64][65];
    int blk = blockIdx.x;
    int st = blk & 15;
    int t2 = blk >> 4;
    int g = t2 & 7;
    int b = t2 >> 3;
    int tid = threadIdx.x;
    int cj = tid & 63;
    int ri = tid >> 6;
    const u16* src = QKV + ((size_t)(b * SS + st * 64)) * 3072 + 2560 + g * 64;
#pragma unroll
    for (int it = 0; it < 16; it++) {
        int s_i = it * 4 + ri;
        tile[s_i][cj] = src[(size_t)s_i * 3072 + cj];
    }
    __syncthreads();
    u16* dst = Vt + ((size_t)(b * KVHN + g) * HDIM) * SS + st * 64;
#pragma unroll
    for (int it = 0; it < 16; it++) {
        int hd_i = it * 4 + ri;
        _Float16 hv = (_Float16)b2f(tile[cj][hd_i]);
        union { _Float16 h; u16 u; } cv; cv.h = hv;
        dst[(size_t)hd_i * SS + cj] = cv.u;
    }
}

// ---------------- Flash attention: 32 q-rows/block, K=32 PV, LDS-staged K/V ----------------
// 1-D grid 1024, 256 threads. XCD-aware decode: each XCD owns 4 (b,g) KV-sets (1 MB, L2-fit).
__global__ __launch_bounds__(256, 4) void flash_kernel(const u16* __restrict__ Qh,
                                                       const u16* __restrict__ Kh,
                                                       const u16* __restrict__ Vt,
                                                       u16* __restrict__ Attn) {
    __shared__ __align__(16) u16 Kls[2][4096];
    __shared__ __align__(16) u16 Vls[2][4096];
    const int tid = threadIdx.x;
    const int lane = tid & 63;
    const int w = tid >> 6;
    const int bid = blockIdx.x;
    const int gbp = ((bid & 7) << 2) | ((bid >> 3) & 3);  // XCD-chunked (b,g) pair
    const int qt = bid >> 5;
    const int g = gbp & 7;
    const int b = gbp >> 3;
    const int h = g * 4 + w;
    const int lr = lane & 15;
    const int lg = lane >> 4;
    const int lk8 = lg * 8;
    const int lq = lg * 4;

    const u16* Qbase = Qh + ((size_t)(b * HH + h) * SS + qt * 32) * HDIM;
    bf16x8 qb[2][2];
#pragma unroll
    for (int j = 0; j < 2; j++) {
        qb[j][0] = *(const bf16x8*)(Qbase + (size_t)(j * 16 + lr) * HDIM + lk8);
        qb[j][1] = *(const bf16x8*)(Qbase + (size_t)(j * 16 + lr) * HDIM + 32 + lk8);
    }

    const u16* Kbase = Kh + (size_t)(b * KVHN + g) * SS * HDIM;
    const u16* Vbase = Vt + (size_t)(b * KVHN + g) * HDIM * SS;

    const int r0 = tid >> 3;
    const int c0 = tid & 7;

    const f32x4 zero4 = {0.f, 0.f, 0.f, 0.f};
    const f32x4 initS = {-4.f, -4.f, -4.f, -4.f};
    f32x4 o[2][4];
    float lsum[2] = {0.f, 0.f};
#pragma unroll
    for (int j = 0; j < 2; j++)
#pragma unroll
        for (int i = 0; i < 4; i++) o[j][i] = zero4;

#define STAGE(kt, p)                                                              \
    {                                                                             \
        _Pragma("unroll") for (int sh = 0; sh < 2; sh++) {                        \
            int rr = r0 + sh * 32;                                                \
            int cs = c0 ^ (rr & 7);                                              \
            async_cp16(Kbase + (size_t)((kt) + rr) * HDIM + cs * 8,               \
                       &Kls[p][sh * 2048 + w * 512]);                             \
            async_cp16(Vbase + (size_t)rr * SS + (kt) + cs * 8,                   \
                       &Vls[p][sh * 2048 + w * 512]);                             \
        }                                                                         \
    }

    STAGE(0, 0);
    __syncthreads();

    for (int t = 0; t < 16; t++) {
        const int p = t & 1;
        if (t < 15) STAGE((t + 1) * 64, p ^ 1);

#pragma unroll
        for (int c = 0; c < 2; c++) {  // two 32-kv chunks per 64-tile
            f32x4 s[2][2];  // [half][j]
#pragma unroll
            for (int halfi = 0; halfi < 2; halfi++) {
                const int R = c * 32 + halfi * 16 + lr;
                const u16* kr = &Kls[p][R * 64];
                bf16x8 kb0 = *(const bf16x8*)(kr + ((lg ^ (R & 7)) * 8));
                bf16x8 kb1 = *(const bf16x8*)(kr + (((4 + lg) ^ (R & 7)) * 8));
#pragma unroll
                for (int j = 0; j < 2; j++) {
                    f32x4 a = initS;
                    a = mfma16(kb0, qb[j][0], a);
                    a = mfma16(kb1, qb[j][1], a);
                    s[halfi][j] = a;
                }
            }

            f16x8 va[4];
#pragma unroll
            for (int hdt = 0; hdt < 4; hdt++) {
                const int R2 = hdt * 16 + lr;
                va[hdt] = *(const f16x8*)(&Vls[p][R2 * 64 + (((c * 4 + lg) ^ (R2 & 7)) * 8)]);
            }

#pragma unroll
            for (int j = 0; j < 2; j++) {
                float pv[8];
#pragma unroll
                for (int r = 0; r < 4; r++) {
                    pv[r] = __builtin_amdgcn_exp2f(s[0][j][r]);
                    pv[4 + r] = __builtin_amdgcn_exp2f(s[1][j][r]);
                }
                lsum[j] += ((pv[0] + pv[1]) + (pv[2] + pv[3])) +
                           ((pv[4] + pv[5]) + (pv[6] + pv[7]));
                f16x8 pb = pack8_f16(pv);
#pragma unroll
                for (int hdt = 0; hdt < 4; hdt++)
                    o[j][hdt] = mfma16h(va[hdt], pb, o[j][hdt]);
            }
        }
        __syncthreads();
    }

#pragma unroll
    for (int j = 0; j < 2; j++) {
        float su = lsum[j];
        su += __shfl_xor(su, 16);
        su += __shfl_xor(su, 32);
        float inv = 1.f / su;
        u16* Ob = Attn + ((size_t)(b * SS + qt * 32 + j * 16 + lr)) * 2048 + h * 64;
#pragma unroll
        for (int hdt = 0; hdt < 4; hdt++) {
            unsigned r0p = (unsigned)f2b(o[j][hdt][0] * inv) | ((unsigned)f2b(o[j][hdt][1] * inv) << 16);
            unsigned r1p = (unsigned)f2b(o[j][hdt][2] * inv) | ((unsigned)f2b(o[j][hdt][3] * inv) << 16);
            *(uint2*)(Ob + hdt * 16 + lq) = make_uint2(r0p, r1p);
        }
    }
}

// ---------------- launch ----------------
extern "C" void kernel_launch(void* const* d_in, const int* in_sizes, int n_in,
                              void* d_out, int out_size, void* d_ws, size_t ws_size,
                              hipStream_t stream) {
    (void)in_sizes; (void)n_in; (void)out_size; (void)ws_size;
    const float* x = (const float*)d_in[0];
    const float* cosT = (const float*)d_in[1];
    const float* sinT = (const float*)d_in[2];
    const float* Wq = (const float*)d_in[3];
    const float* Wk = (const float*)d_in[4];
    const float* Wv = (const float*)d_in[5];
    const float* Wo = (const float*)d_in[6];
    float* out = (float*)d_out;

    char* ws = (char*)d_ws;
    u16* Xb    = (u16*)(ws);                    // 16 MB
    u16* Wqkvt = (u16*)(ws + 16777216);         // 12 MB
    u16* Wot   = (u16*)(ws + 29360128);         // 8 MB
    u16* QKV   = (u16*)(ws + 37748736);         // 24 MB
    u16* Qh    = (u16*)(ws + 62914560);         // 16 MB
    u16* Kh    = (u16*)(ws + 79691776);         // 4 MB
    u16* Vt    = (u16*)(ws + 83886080);         // 4 MB (f16 bits)
    u16* Attn  = (u16*)(ws + 88080384);         // 16 MB

    cast_x_kernel<<<8192, 256, 0, stream>>>(x, Xb);
    wtrans_all_kernel<<<dim3(64, 64, 4), 256, 0, stream>>>(Wq, Wk, Wv, Wo, Wqkvt, Wot);

    gemm_qkv<<<512, 256, 0, stream>>>(Xb, Wqkvt, QKV);

    rope_kernel<<<20480, 256, 0, stream>>>(QKV, cosT, sinT, Qh, Kh);
    vtrans_kernel<<<512, 256, 0, stream>>>(QKV, Vt);

    flash_kernel<<<1024, 256, 0, stream>>>(Qh, Kh, Vt, Attn);

    gemm_out<<<512, 256, 0, stream>>>(Attn, Wot, out);
}

// Round 4
// 270.515 us; speedup vs baseline: 1.0309x; 1.0309x over previous
//
#include <hip/hip_runtime.h>

typedef unsigned short u16;
typedef __attribute__((ext_vector_type(8))) __bf16 bf16x8;
typedef __attribute__((ext_vector_type(4))) _Float16 f16x4;
typedef __attribute__((ext_vector_type(8))) _Float16 f16x8;
typedef __attribute__((ext_vector_type(4))) float f32x4;

#define BB 4
#define SS 1024
#define DD 2048
#define HH 32
#define KVHN 8
#define HDIM 64

__device__ __forceinline__ u16 f2b(float f) {
    union { float f; unsigned u; } v; v.f = f;
    unsigned r = v.u + 0x7FFFu + ((v.u >> 16) & 1u);
    return (u16)(r >> 16);
}
__device__ __forceinline__ float b2f(u16 h) {
    union { unsigned u; float f; } v; v.u = ((unsigned)h) << 16; return v.f;
}

__device__ __forceinline__ f32x4 mfma16(bf16x8 a, bf16x8 b, f32x4 c) {
    return __builtin_amdgcn_mfma_f32_16x16x32_bf16(a, b, c, 0, 0, 0);
}
__device__ __forceinline__ f32x4 mfma16h(f16x8 a, f16x8 b, f32x4 c) {
    return __builtin_amdgcn_mfma_f32_16x16x32_f16(a, b, c, 0, 0, 0);
}

__device__ __forceinline__ void async_cp16(const void* g, void* l) {
    __builtin_amdgcn_global_load_lds((__attribute__((address_space(1))) void*)g,
                                     (__attribute__((address_space(3))) void*)l,
                                     16, 0, 0);
}

// raw barrier WITHOUT the compiler's vmcnt(0) drain
__device__ __forceinline__ void block_sync() {
    asm volatile("" ::: "memory");
    __builtin_amdgcn_s_barrier();
    asm volatile("" ::: "memory");
}

// pack 8 floats -> f16x8 via v_cvt_pkrtz
__device__ __forceinline__ f16x8 pack8_f16(const float* p) {
    union { unsigned u[4]; f16x8 v; } pu;
    pu.u[0] = __builtin_bit_cast(unsigned, __builtin_amdgcn_cvt_pkrtz(p[0], p[1]));
    pu.u[1] = __builtin_bit_cast(unsigned, __builtin_amdgcn_cvt_pkrtz(p[2], p[3]));
    pu.u[2] = __builtin_bit_cast(unsigned, __builtin_amdgcn_cvt_pkrtz(p[4], p[5]));
    pu.u[3] = __builtin_bit_cast(unsigned, __builtin_amdgcn_cvt_pkrtz(p[6], p[7]));
    return pu.v;
}

// ---------------- cast x (fp32 -> bf16) ----------------
__global__ __launch_bounds__(256) void cast_x_kernel(const float* __restrict__ x,
                                                     u16* __restrict__ xb) {
    int i = (blockIdx.x * 256 + threadIdx.x) * 4;
    float4 v = *(const float4*)(x + i);
    unsigned r0 = (unsigned)f2b(v.x) | ((unsigned)f2b(v.y) << 16);
    unsigned r1 = (unsigned)f2b(v.z) | ((unsigned)f2b(v.w) << 16);
    *(uint2*)(xb + i) = make_uint2(r0, r1);
}

// ---------------- all weight transposes in one launch ----------------
__global__ __launch_bounds__(256) void wtrans_all_kernel(const float* __restrict__ Wq,
                                                         const float* __restrict__ Wk,
                                                         const float* __restrict__ Wv,
                                                         const float* __restrict__ Wo,
                                                         u16* __restrict__ Wqkvt,
                                                         u16* __restrict__ Wot) {
    __shared__ float tile[32][33];
    int z = blockIdx.z;
    const float* W = (z == 0) ? Wq : (z == 1) ? Wk : (z == 2) ? Wv : Wo;
    int N = (z == 1 || z == 2) ? 512 : 2048;
    int n_off = (z == 1) ? 2048 : (z == 2) ? 2560 : 0;
    u16* Wt = (z == 3) ? Wot : Wqkvt;
    int n0 = blockIdx.x * 32;
    if (n0 >= N) return;
    int k0 = blockIdx.y * 32;
    int tid = threadIdx.x;
    int nj = tid & 31;
    int ki = tid >> 5;
#pragma unroll
    for (int it = 0; it < 4; it++) {
        int kk = it * 8 + ki;
        tile[kk][nj] = W[(size_t)(k0 + kk) * N + n0 + nj];
    }
    __syncthreads();
#pragma unroll
    for (int it = 0; it < 4; it++) {
        int nn = it * 8 + ki;
        Wt[(size_t)(n0 + nn + n_off) * 2048 + k0 + nj] = f2b(tile[nj][nn]);
    }
}

// ============================================================================
// GEMM (qkv): C[4096][3072](bf16) = A[4096][2048] * Bt[3072][2048]^T
// Fine-phase schedule: 256x256 tile, BK=64, 8 waves (2Mx4N),
// LDS 2 x (A 32KB + B 32KB) dbuf, chunk = kslice (16KB, 2 loads/thread),
// 4 phases/K-tile x 16 MFMA, vmcnt(4) once per K-tile, setprio clusters.
// Phase: {ds_reads ; stage 1 chunk ; barrier ; lgkmcnt(0) ; 16 MFMA ; barrier}
// Ledger: chunk overwrite >=1 drained phase after last read; end-of-tile
// vmcnt(4) leaves exactly tile T+2's ks0 (4 loads) in flight.
// Prologue stages tile0 full + tile1-ks0 ONLY (iter 0 stages tile1-ks1 and
// tile2-ks0 itself — pre-staging tile2 was round-3's race).
// ============================================================================
__global__ __launch_bounds__(512, 2) void gemm_qkv(const u16* __restrict__ A,
                                                   const u16* __restrict__ Bt,
                                                   u16* __restrict__ C) {
    __shared__ __align__(16) u16 Ls[2][32768];  // per buf: A ks0|ks1 @0/8192, B @16384/24576
    const int tid = threadIdx.x;
    const int lane = tid & 63;
    const int w = tid >> 6;

    // 192 blocks; XCD owns 4m x 6n super-tile
    const int bid = blockIdx.x;
    const int xcd = bid & 7;
    const int loc = bid >> 3;            // 0..23
    const int mt = (xcd & 3) * 4 + (loc & 3);    // 0..15
    const int nt = (xcd >> 2) * 6 + (loc >> 2);  // 0..11
    const int m0 = mt * 256;
    const int n0 = nt * 256;

    const int wm = (w >> 2) * 128;  // 2 M-wave-rows
    const int wn = (w & 3) * 64;    // 4 N-wave-cols
    const int lr = lane & 15;
    const int lg = lane >> 4;

    // staging: chunk = [256 rows][32 cols] bf16 = 16KB = 512thr x 2 x 16B
    const int row0 = tid >> 2;
    const int g = tid & 3;
    const int sg = g ^ ((row0 >> 1) & 3);      // same for row0+128
    const u16* pA0 = A + (size_t)(m0 + row0) * 2048 + sg * 8;
    const u16* pA1 = pA0 + (size_t)128 * 2048;
    const u16* pB0 = Bt + (size_t)(n0 + row0) * 2048 + sg * 8;
    const u16* pB1 = pB0 + (size_t)128 * 2048;

#define QSTA(buf_, ks_, T_)                                                     \
    {                                                                           \
        async_cp16(pA0 + (T_) * 64 + (ks_) * 32, &Ls[buf_][(ks_) * 8192 + w * 512]);        \
        async_cp16(pA1 + (T_) * 64 + (ks_) * 32, &Ls[buf_][(ks_) * 8192 + 4096 + w * 512]); \
    }
#define QSTB(buf_, ks_, T_)                                                     \
    {                                                                           \
        async_cp16(pB0 + (T_) * 64 + (ks_) * 32, &Ls[buf_][16384 + (ks_) * 8192 + w * 512]);        \
        async_cp16(pB1 + (T_) * 64 + (ks_) * 32, &Ls[buf_][16384 + (ks_) * 8192 + 4096 + w * 512]); \
    }

    f32x4 acc[8][4];
    const f32x4 zero4 = {0.f, 0.f, 0.f, 0.f};
#pragma unroll
    for (int i = 0; i < 8; i++)
#pragma unroll
        for (int j = 0; j < 4; j++) acc[i][j] = zero4;

    bf16x8 af[8], bfr[4];

#define QLDA(ks_)                                                               \
    _Pragma("unroll") for (int mi = 0; mi < 8; mi++) {                          \
        int r_ = wm + mi * 16 + lr;                                             \
        af[mi] = *(const bf16x8*)(&Ls[cur][(ks_) * 8192 + r_ * 32 + ((lg ^ ((r_ >> 1) & 3)) * 8)]); \
    }
#define QLDB(ks_, nb_)                                                          \
    _Pragma("unroll") for (int q_ = 0; q_ < 2; q_++) {                          \
        int ni_ = (nb_) * 2 + q_;                                               \
        int r_ = wn + ni_ * 16 + lr;                                            \
        bfr[ni_] = *(const bf16x8*)(&Ls[cur][16384 + (ks_) * 8192 + r_ * 32 + ((lg ^ ((r_ >> 1) & 3)) * 8)]); \
    }
#define QMM(nb_)                                                                \
    __builtin_amdgcn_s_setprio(1);                                              \
    _Pragma("unroll") for (int mi = 0; mi < 8; mi++) _Pragma("unroll") for (int q_ = 0; q_ < 2; q_++) { \
        int ni_ = (nb_) * 2 + q_;                                               \
        acc[mi][ni_] = mfma16(af[mi], bfr[ni_], acc[mi][ni_]);                  \
    }                                                                           \
    __builtin_amdgcn_s_setprio(0);
#define QWAITMM                                                                 \
    asm volatile("s_waitcnt lgkmcnt(0)" ::: "memory");                          \
    __builtin_amdgcn_sched_barrier(0);

    // prologue: tile0 full + tile1-ks0 (12 loads). vmcnt(4): tile0's 8 landed,
    // tile1-ks0's 4 may still fly (certified by end-of-iter-0 vmcnt).
    QSTA(0, 0, 0); QSTB(0, 0, 0); QSTA(0, 1, 0); QSTB(0, 1, 0);
    QSTA(1, 0, 1); QSTB(1, 0, 1);
    asm volatile("s_waitcnt vmcnt(4)" ::: "memory");
    block_sync();

#pragma unroll 2
    for (int T = 0; T < 32; ++T) {
        const int cur = T & 1;
        const int oth = cur ^ 1;
        const int Tp1 = (T + 1) & 31;  // tail wrap: redundant, never read
        const int Tp2 = (T + 2) & 31;

        // ---- phase 1: ks0, n-frags 0-1 ----
        QLDA(0); QLDB(0, 0);
        QSTA(oth, 1, Tp1);            // overwrites tile T-1 A-ks1 (dead since its ph3/4)
        block_sync(); QWAITMM;
        QMM(0);
        block_sync();
        // ---- phase 2: ks0, n-frags 2-3 ----
        QLDB(0, 1);
        QSTB(oth, 1, Tp1);            // overwrites tile T-1 B-ks1 (dead)
        block_sync(); QWAITMM;
        QMM(1);
        block_sync();
        // ---- phase 3: ks1, n-frags 0-1 ----
        QLDA(1); QLDB(1, 0);
        QSTA(cur, 0, Tp2);            // overwrites tile T A-ks0 (read in ph1-2, drained)
        block_sync(); QWAITMM;
        QMM(0);
        block_sync();
        // ---- phase 4: ks1, n-frags 2-3 ----
        QLDB(1, 1);
        QSTB(cur, 0, Tp2);            // overwrites tile T B-ks0 (read in ph1-2, drained)
        block_sync(); QWAITMM;
        QMM(1);
        // certify tile T+1 (ks0 chunks of T+2 = 4 newest loads stay in flight)
        asm volatile("s_waitcnt vmcnt(4)" ::: "memory");
        block_sync();
    }
    asm volatile("s_waitcnt vmcnt(0)" ::: "memory");  // drain DMA before retire

    const int lq = lg * 4;
#pragma unroll
    for (int mi = 0; mi < 8; mi++)
#pragma unroll
        for (int ni = 0; ni < 4; ni++)
#pragma unroll
            for (int i = 0; i < 4; i++) {
                int r = m0 + wm + mi * 16 + lq + i;
                int c = n0 + wn + ni * 16 + lr;
                C[(size_t)r * 3072 + c] = f2b(acc[mi][ni][i]);
            }
#undef QSTA
#undef QSTB
#undef QLDA
#undef QLDB
#undef QMM
#undef QWAITMM
}

// ============================================================================
// GEMM (out): C[4096][2048](f32) = A[4096][2048](bf16) * Bt[2048][2048]^T
// Same fine-phase schedule: 256x128 tile, BK=64, 8 waves (2Mx4N, wave 128x32),
// LDS 2 x (A 32KB + B 16KB), 2 phases/K-tile x 16 MFMA, vmcnt(3) per K-tile.
// Grid 16x16 = 256 blocks = all CUs, XCD 4m x 8n super-tiles.
// Prologue: tile0 full + tile1-ks0 only (9 loads).
// ============================================================================
__global__ __launch_bounds__(512, 2) void gemm_out(const u16* __restrict__ A,
                                                   const u16* __restrict__ Bt,
                                                   float* __restrict__ C) {
    __shared__ __align__(16) u16 Ls[2][24576];  // A ks0|ks1 @0/8192, B ks0|ks1 @16384/20480
    const int tid = threadIdx.x;
    const int lane = tid & 63;
    const int w = tid >> 6;

    const int bid = blockIdx.x;
    const int xcd = bid & 7;
    const int loc = bid >> 3;            // 0..31
    const int mt = (xcd & 3) * 4 + (loc & 3);    // 0..15
    const int nt = (xcd >> 2) * 8 + (loc >> 2);  // 0..15
    const int m0 = mt * 256;
    const int n0 = nt * 128;

    const int wm = (w >> 2) * 128;
    const int wn = (w & 3) * 32;
    const int lr = lane & 15;
    const int lg = lane >> 4;

    const int row0 = tid >> 2;
    const int g = tid & 3;
    const int sg = g ^ ((row0 >> 1) & 3);
    const u16* pA0 = A + (size_t)(m0 + row0) * 2048 + sg * 8;
    const u16* pA1 = pA0 + (size_t)128 * 2048;
    const u16* pB0 = Bt + (size_t)(n0 + row0) * 2048 + sg * 8;  // B chunk: 128 rows, 1 load/thr

#define OSTA(buf_, ks_, T_)                                                     \
    {                                                                           \
        async_cp16(pA0 + (T_) * 64 + (ks_) * 32, &Ls[buf_][(ks_) * 8192 + w * 512]);        \
        async_cp16(pA1 + (T_) * 64 + (ks_) * 32, &Ls[buf_][(ks_) * 8192 + 4096 + w * 512]); \
    }
#define OSTB(buf_, ks_, T_)                                                     \
    {                                                                           \
        async_cp16(pB0 + (T_) * 64 + (ks_) * 32, &Ls[buf_][16384 + (ks_) * 4096 + w * 512]); \
    }

    f32x4 acc[8][2];
    const f32x4 zero4 = {0.f, 0.f, 0.f, 0.f};
#pragma unroll
    for (int i = 0; i < 8; i++)
#pragma unroll
        for (int j = 0; j < 2; j++) acc[i][j] = zero4;

    bf16x8 af[8], bfr[2];

#define OLDA(ks_)                                                               \
    _Pragma("unroll") for (int mi = 0; mi < 8; mi++) {                          \
        int r_ = wm + mi * 16 + lr;                                             \
        af[mi] = *(const bf16x8*)(&Ls[cur][(ks_) * 8192 + r_ * 32 + ((lg ^ ((r_ >> 1) & 3)) * 8)]); \
    }
#define OLDB(ks_)                                                               \
    _Pragma("unroll") for (int ni = 0; ni < 2; ni++) {                          \
        int r_ = wn + ni * 16 + lr;                                             \
        bfr[ni] = *(const bf16x8*)(&Ls[cur][16384 + (ks_) * 4096 + r_ * 32 + ((lg ^ ((r_ >> 1) & 3)) * 8)]); \
    }
#define OMM                                                                     \
    __builtin_amdgcn_s_setprio(1);                                              \
    _Pragma("unroll") for (int mi = 0; mi < 8; mi++) _Pragma("unroll") for (int ni = 0; ni < 2; ni++) { \
        acc[mi][ni] = mfma16(af[mi], bfr[ni], acc[mi][ni]);                     \
    }                                                                           \
    __builtin_amdgcn_s_setprio(0);
#define OWAITMM                                                                 \
    asm volatile("s_waitcnt lgkmcnt(0)" ::: "memory");                          \
    __builtin_amdgcn_sched_barrier(0);

    // prologue: tile0 full + tile1-ks0 (9 loads); vmcnt(3): tile0's 6 landed.
    OSTA(0, 0, 0); OSTB(0, 0, 0); OSTA(0, 1, 0); OSTB(0, 1, 0);
    OSTA(1, 0, 1); OSTB(1, 0, 1);
    asm volatile("s_waitcnt vmcnt(3)" ::: "memory");
    block_sync();

#pragma unroll 2
    for (int T = 0; T < 32; ++T) {
        const int cur = T & 1;
        const int oth = cur ^ 1;
        const int Tp1 = (T + 1) & 31;
        const int Tp2 = (T + 2) & 31;

        // ---- phase 1: ks0 ----
        OLDA(0); OLDB(0);
        OSTA(oth, 1, Tp1); OSTB(oth, 1, Tp1);   // tile T-1 ks1 regions (dead)
        block_sync(); OWAITMM;
        OMM;
        block_sync();
        // ---- phase 2: ks1 ----
        OLDA(1); OLDB(1);
        OSTA(cur, 0, Tp2); OSTB(cur, 0, Tp2);   // tile T ks0 regions (read ph1, drained)
        block_sync(); OWAITMM;
        OMM;
        asm volatile("s_waitcnt vmcnt(3)" ::: "memory");  // certify tile T+1
        block_sync();
    }
    asm volatile("s_waitcnt vmcnt(0)" ::: "memory");

    const int lq = lg * 4;
#pragma unroll
    for (int mi = 0; mi < 8; mi++)
#pragma unroll
        for (int ni = 0; ni < 2; ni++)
#pragma unroll
            for (int i = 0; i < 4; i++) {
                int r = m0 + wm + mi * 16 + lq + i;
                int c = n0 + wn + ni * 16 + lr;
                C[(size_t)r * 2048 + c] = acc[mi][ni][i];
            }
#undef OSTA
#undef OSTB
#undef OLDA
#undef OLDB
#undef OMM
#undef OWAITMM
}

// ---------------- RoPE + reshape.  Q pre-scaled by 0.125*log2(e).
// K rows permuted within each 32-seq block so QK S-tiles emit the K=32 PV B-layout:
// row = (s&~31) + (rr>=4)*16 + ((s>>3)&3)*4 + (rr&3), rr = s&7.
__global__ __launch_bounds__(256) void rope_kernel(const u16* __restrict__ QKV,
                                                   const float* __restrict__ cosT,
                                                   const float* __restrict__ sinT,
                                                   u16* __restrict__ Qh,
                                                   u16* __restrict__ Kh) {
    const float QSC = 0.125f * 1.44269504088896f;
    int idx = blockIdx.x * 256 + threadIdx.x;
    int d = idx & 31;
    int t = idx >> 5;
    int hh = t % 40;
    int row = t / 40;
    int s = row & (SS - 1);
    int b = row >> 10;
    float c = cosT[s * HDIM + d];
    float sn = sinT[s * HDIM + d];
    if (hh < 32) {
        const u16* src = QKV + (size_t)row * 3072 + hh * 64 + d;
        float x1 = b2f(src[0]), x2 = b2f(src[32]);
        u16* dst = Qh + ((size_t)(b * HH + hh) * SS + s) * 64 + d;
        dst[0] = f2b((x1 * c - x2 * sn) * QSC);
        dst[32] = f2b((x2 * c + x1 * sn) * QSC);
    } else {
        int g = hh - 32;
        const u16* src = QKV + (size_t)row * 3072 + 2048 + g * 64 + d;
        float x1 = b2f(src[0]), x2 = b2f(src[32]);
        int rr = s & 7;
        int kpos = (s & ~31) + ((rr >= 4) ? 16 : 0) + ((s >> 3) & 3) * 4 + (rr & 3);
        u16* dst = Kh + ((size_t)(b * KVHN + g) * SS + kpos) * 64 + d;
        dst[0] = f2b(x1 * c - x2 * sn);
        dst[32] = f2b(x2 * c + x1 * sn);
    }
}

// ---------------- V transpose: QKV bf16 -> Vt[B][KVH][64][S] f16 (identity kv order) ----------------
__global__ __launch_bounds__(256) void vtrans_kernel(const u16* __restrict__ QKV,
                                                     u16* __restrict__ Vt) {
    __shared__ u16 tile[64][65];
    int blk = blockIdx.x;
    int st = blk & 15;
    int t2 = blk >> 4;
    int g = t2 & 7;
    int b = t2 >> 3;
    int tid = threadIdx.x;
    int cj = tid & 63;
    int ri = tid >> 6;
    const u16* src = QKV + ((size_t)(b * SS + st * 64)) * 3072 + 2560 + g * 64;
#pragma unroll
    for (int it = 0; it < 16; it++) {
        int s_i = it * 4 + ri;
        tile[s_i][cj] = src[(size_t)s_i * 3072 + cj];
    }
    __syncthreads();
    u16* dst = Vt + ((size_t)(b * KVHN + g) * HDIM) * SS + st * 64;
#pragma unroll
    for (int it = 0; it < 16; it++) {
        int hd_i = it * 4 + ri;
        _Float16 hv = (_Float16)b2f(tile[cj][hd_i]);
        union { _Float16 h; u16 u; } cv; cv.h = hv;
        dst[(size_t)hd_i * SS + cj] = cv.u;
    }
}

// ---------------- Flash attention: 32 q-rows/block, K=32 PV, LDS-staged K/V ----------------
// 1-D grid 1024, 256 threads. XCD-aware decode: each XCD owns 4 (b,g) KV-sets (1 MB, L2-fit).
__global__ __launch_bounds__(256, 4) void flash_kernel(const u16* __restrict__ Qh,
                                                       const u16* __restrict__ Kh,
                                                       const u16* __restrict__ Vt,
                                                       u16* __restrict__ Attn) {
    __shared__ __align__(16) u16 Kls[2][4096];
    __shared__ __align__(16) u16 Vls[2][4096];
    const int tid = threadIdx.x;
    const int lane = tid & 63;
    const int w = tid >> 6;
    const int bid = blockIdx.x;
    const int gbp = ((bid & 7) << 2) | ((bid >> 3) & 3);  // XCD-chunked (b,g) pair
    const int qt = bid >> 5;
    const int g = gbp & 7;
    const int b = gbp >> 3;
    const int h = g * 4 + w;
    const int lr = lane & 15;
    const int lg = lane >> 4;
    const int lk8 = lg * 8;
    const int lq = lg * 4;

    const u16* Qbase = Qh + ((size_t)(b * HH + h) * SS + qt * 32) * HDIM;
    bf16x8 qb[2][2];
#pragma unroll
    for (int j = 0; j < 2; j++) {
        qb[j][0] = *(const bf16x8*)(Qbase + (size_t)(j * 16 + lr) * HDIM + lk8);
        qb[j][1] = *(const bf16x8*)(Qbase + (size_t)(j * 16 + lr) * HDIM + 32 + lk8);
    }

    const u16* Kbase = Kh + (size_t)(b * KVHN + g) * SS * HDIM;
    const u16* Vbase = Vt + (size_t)(b * KVHN + g) * HDIM * SS;

    const int r0 = tid >> 3;
    const int c0 = tid & 7;

    const f32x4 zero4 = {0.f, 0.f, 0.f, 0.f};
    const f32x4 initS = {-4.f, -4.f, -4.f, -4.f};
    f32x4 o[2][4];
    float lsum[2] = {0.f, 0.f};
#pragma unroll
    for (int j = 0; j < 2; j++)
#pragma unroll
        for (int i = 0; i < 4; i++) o[j][i] = zero4;

#define STAGE(kt, p)                                                              \
    {                                                                             \
        _Pragma("unroll") for (int sh = 0; sh < 2; sh++) {                        \
            int rr = r0 + sh * 32;                                                \
            int cs = c0 ^ (rr & 7);                                              \
            async_cp16(Kbase + (size_t)((kt) + rr) * HDIM + cs * 8,               \
                       &Kls[p][sh * 2048 + w * 512]);                             \
            async_cp16(Vbase + (size_t)rr * SS + (kt) + cs * 8,                   \
                       &Vls[p][sh * 2048 + w * 512]);                             \
        }                                                                         \
    }

    STAGE(0, 0);
    __syncthreads();

    for (int t = 0; t < 16; t++) {
        const int p = t & 1;
        if (t < 15) STAGE((t + 1) * 64, p ^ 1);

#pragma unroll
        for (int c = 0; c < 2; c++) {  // two 32-kv chunks per 64-tile
            f32x4 s[2][2];  // [half][j]
#pragma unroll
            for (int halfi = 0; halfi < 2; halfi++) {
                const int R = c * 32 + halfi * 16 + lr;
                const u16* kr = &Kls[p][R * 64];
                bf16x8 kb0 = *(const bf16x8*)(kr + ((lg ^ (R & 7)) * 8));
                bf16x8 kb1 = *(const bf16x8*)(kr + (((4 + lg) ^ (R & 7)) * 8));
#pragma unroll
                for (int j = 0; j < 2; j++) {
                    f32x4 a = initS;
                    a = mfma16(kb0, qb[j][0], a);
                    a = mfma16(kb1, qb[j][1], a);
                    s[halfi][j] = a;
                }
            }

            f16x8 va[4];
#pragma unroll
            for (int hdt = 0; hdt < 4; hdt++) {
                const int R2 = hdt * 16 + lr;
                va[hdt] = *(const f16x8*)(&Vls[p][R2 * 64 + (((c * 4 + lg) ^ (R2 & 7)) * 8)]);
            }

#pragma unroll
            for (int j = 0; j < 2; j++) {
                float pv[8];
#pragma unroll
                for (int r = 0; r < 4; r++) {
                    pv[r] = __builtin_amdgcn_exp2f(s[0][j][r]);
                    pv[4 + r] = __builtin_amdgcn_exp2f(s[1][j][r]);
                }
                lsum[j] += ((pv[0] + pv[1]) + (pv[2] + pv[3])) +
                           ((pv[4] + pv[5]) + (pv[6] + pv[7]));
                f16x8 pb = pack8_f16(pv);
#pragma unroll
                for (int hdt = 0; hdt < 4; hdt++)
                    o[j][hdt] = mfma16h(va[hdt], pb, o[j][hdt]);
            }
        }
        __syncthreads();
    }

#pragma unroll
    for (int j = 0; j < 2; j++) {
        float su = lsum[j];
        su += __shfl_xor(su, 16);
        su += __shfl_xor(su, 32);
        float inv = 1.f / su;
        u16* Ob = Attn + ((size_t)(b * SS + qt * 32 + j * 16 + lr)) * 2048 + h * 64;
#pragma unroll
        for (int hdt = 0; hdt < 4; hdt++) {
            unsigned r0p = (unsigned)f2b(o[j][hdt][0] * inv) | ((unsigned)f2b(o[j][hdt][1] * inv) << 16);
            unsigned r1p = (unsigned)f2b(o[j][hdt][2] * inv) | ((unsigned)f2b(o[j][hdt][3] * inv) << 16);
            *(uint2*)(Ob + hdt * 16 + lq) = make_uint2(r0p, r1p);
        }
    }
}

// ---------------- launch ----------------
extern "C" void kernel_launch(void* const* d_in, const int* in_sizes, int n_in,
                              void* d_out, int out_size, void* d_ws, size_t ws_size,
                              hipStream_t stream) {
    (void)in_sizes; (void)n_in; (void)out_size; (void)ws_size;
    const float* x = (const float*)d_in[0];
    const float* cosT = (const float*)d_in[1];
    const float* sinT = (const float*)d_in[2];
    const float* Wq = (const float*)d_in[3];
    const float* Wk = (const float*)d_in[4];
    const float* Wv = (const float*)d_in[5];
    const float* Wo = (const float*)d_in[6];
    float* out = (float*)d_out;

    char* ws = (char*)d_ws;
    u16* Xb    = (u16*)(ws);                    // 16 MB
    u16* Wqkvt = (u16*)(ws + 16777216);         // 12 MB
    u16* Wot   = (u16*)(ws + 29360128);         // 8 MB
    u16* QKV   = (u16*)(ws + 37748736);         // 24 MB
    u16* Qh    = (u16*)(ws + 62914560);         // 16 MB
    u16* Kh    = (u16*)(ws + 79691776);         // 4 MB
    u16* Vt    = (u16*)(ws + 83886080);         // 4 MB (f16 bits)
    u16* Attn  = (u16*)(ws + 88080384);         // 16 MB

    cast_x_kernel<<<8192, 256, 0, stream>>>(x, Xb);
    wtrans_all_kernel<<<dim3(64, 64, 4), 256, 0, stream>>>(Wq, Wk, Wv, Wo, Wqkvt, Wot);

    gemm_qkv<<<192, 512, 0, stream>>>(Xb, Wqkvt, QKV);

    rope_kernel<<<20480, 256, 0, stream>>>(QKV, cosT, sinT, Qh, Kh);
    vtrans_kernel<<<512, 256, 0, stream>>>(QKV, Vt);

    flash_kernel<<<1024, 256, 0, stream>>>(Qh, Kh, Vt, Attn);

    gemm_out<<<256, 512, 0, stream>>>(Attn, Wot, out);
}